// Round 4
// baseline (677.977 us; speedup 1.0000x reference)
//
#include <hip/hip_runtime.h>
#include <hip/hip_bf16.h>
#include <math.h>

#define T_LEN 32768
#define NB 4
#define NC 64
#define NL 18
#define TILE_T 64

typedef __attribute__((ext_vector_type(8))) short s16x8;
typedef __attribute__((ext_vector_type(4))) float f32x4;
#define MFMA_BF16 __builtin_amdgcn_mfma_f32_16x16x32_bf16

__device__ inline unsigned short f2bf(float f) {
    unsigned u = __builtin_bit_cast(unsigned, f);
    unsigned r = u + 0x7FFFu + ((u >> 16) & 1u);
    return (unsigned short)(r >> 16);
}
__device__ inline unsigned pack_bf2(float a, float b) {
    __hip_bfloat162 h = __float22bfloat162_rn(make_float2(a, b));
    unsigned u;
    __builtin_memcpy(&u, &h, 4);
    return u;
}
__device__ inline float bf2f(unsigned short u) {
    return __builtin_bit_cast(float, (unsigned)u << 16);
}
__device__ inline float fast_sigmoid(float x) {
    return __builtin_amdgcn_rcpf(1.f + __expf(-x));
}
__device__ inline float fast_tanh(float x) {
    return 1.f - 2.f * __builtin_amdgcn_rcpf(1.f + __expf(2.f * x));
}

// ------------------------------------------------------------------
// prep: A0[b][t][c] = x*in_w+in_b ; Wh bf16 [L][128co][192K] (K=k*64+ci);
//       Wr bf16 [L][64co][64ci] ; out init = mix_b
// ------------------------------------------------------------------
__global__ void prep_kernel(const float* __restrict__ x,
                            const float* __restrict__ in_w,
                            const float* __restrict__ in_b,
                            const float* __restrict__ hid_w,
                            const float* __restrict__ res_w,
                            const float* __restrict__ mix_b,
                            float* __restrict__ A0,
                            unsigned short* __restrict__ Wh,
                            unsigned short* __restrict__ Wr,
                            float* __restrict__ out) {
    const int nAct = NB * T_LEN * NC;      // 8388608
    const int nW1 = NL * 128 * 192;        // 442368
    const int nW2 = NL * 64 * 64;          // 73728
    const int nOut = NB * T_LEN;           // 131072
    const int total = nAct + nW1 + nW2 + nOut;
    for (int gid = blockIdx.x * blockDim.x + threadIdx.x; gid < total;
         gid += gridDim.x * blockDim.x) {
        if (gid < nAct) {
            int c = gid & 63;
            int t = (gid >> 6) & (T_LEN - 1);
            int b = gid >> 21;
            A0[gid] = x[b * T_LEN + t] * in_w[c] + in_b[c];
        } else if (gid < nAct + nW1) {
            int q = gid - nAct;
            int K = q % 192;
            int co = (q / 192) & 127;
            int i = q / (192 * 128);
            int kt = K >> 6, ci = K & 63;
            Wh[q] = f2bf(hid_w[((i * 128 + co) * 64 + ci) * 3 + kt]);
        } else if (gid < nAct + nW1 + nW2) {
            int q = gid - (nAct + nW1);
            int c = q & 63, co = (q >> 6) & 63, i = q >> 12;
            Wr[q] = f2bf(res_w[(i * 64 + co) * 64 + c]);
        } else {
            out[gid - (nAct + nW1 + nW2)] = mix_b[0];
        }
    }
}

// ------------------------------------------------------------------
// fused layer, MFMA version. block = 256 thr = 4 waves; tile = (b, 64 t).
// wave w owns hid-co {16w..16w+15} u {64+16w..}, res-co {16w..16w+15}.
// X staging: dil<64 -> single union tile [t0-2d, t0+64) (rows r, t = r-2d);
//            dil>=64 -> 3 disjoint tap tiles (row = 64k+t). Both <=192 rows.
// ------------------------------------------------------------------
__launch_bounds__(256, 5)
__global__ void layer_kernel(const float* __restrict__ actIn,
                             float* __restrict__ actOut,
                             const unsigned short* __restrict__ Wh, // [128][192]
                             const float* __restrict__ hb,          // [128]
                             const unsigned short* __restrict__ Wr, // [64][64]
                             const float* __restrict__ rb,          // [64]
                             const float* __restrict__ mw,          // [64]
                             float* __restrict__ skip,              // [B][T]
                             int dil) {
    __shared__ uint4 Xs[1536];     // up to 192 rows x 64ci bf16, XOR-swizzled
    __shared__ uint4 Gs[512];      // gated [64t][64c] bf16, XOR-swizzled

    const int tid = threadIdx.x;
    const int w = tid >> 6;
    const int l = tid & 63;
    const int lo = l & 15;
    const int hi = l >> 4;
    const int b = blockIdx.y;
    // XCD-chunked swizzle: xcd = blockIdx.x % 8 owns contiguous tile range
    const int tile = (blockIdx.x & 7) * 64 + (blockIdx.x >> 3);
    const int t0 = tile * TILE_T;
    const float* actB = actIn + (size_t)b * T_LEN * NC;
    const int m0 = 16 * w;
    const bool uni = (dil < 64);

    // ---- W fragments -> registers ----
    s16x8 AH[2][6];
    s16x8 AR[2];
#pragma unroll
    for (int mt = 0; mt < 2; mt++) {
        const unsigned short* wp = Wh + (size_t)(m0 + 64 * mt + lo) * 192;
#pragma unroll
        for (int s = 0; s < 6; s++)
            AH[mt][s] = *(const s16x8*)(wp + 32 * s + 8 * hi);
    }
#pragma unroll
    for (int s = 0; s < 2; s++)
        AR[s] = *(const s16x8*)(Wr + (size_t)(m0 + lo) * 64 + 32 * s + 8 * hi);

    float bA[4], bB[4], rbv[4];
#pragma unroll
    for (int r = 0; r < 4; r++) {
        bA[r] = hb[m0 + 4 * hi + r];
        bB[r] = hb[64 + m0 + 4 * hi + r];
        rbv[r] = rb[m0 + 4 * hi + r];
    }

    // ---- stage X: fp32 [t][c] -> bf16 LDS rows, swizzled ----
    const int R = uni ? (64 + 2 * dil) : 192;
    for (int p = tid; p < R * 16; p += 256) {
        int row = p >> 4, c4 = p & 15;
        int tg = t0 + (uni ? (row - 2 * dil)
                           : (((row >> 6) - 2) * dil + (row & 63)));
        float4 v = make_float4(0.f, 0.f, 0.f, 0.f);
        if (tg >= 0) v = *(const float4*)(actB + (size_t)tg * 64 + c4 * 4);
        unsigned u0 = pack_bf2(v.x, v.y);
        unsigned u1 = pack_bf2(v.z, v.w);
        int byte = (row * 128 + c4 * 8) ^ ((row & 7) << 4);
        ((uint2*)Xs)[byte >> 3] = make_uint2(u0, u1);
    }
    __syncthreads();

    // ---- hid GEMM: acc[mt][nt] over K=192 (3 taps x 64 ci) ----
    f32x4 acc[2][4];
#pragma unroll
    for (int mt = 0; mt < 2; mt++)
#pragma unroll
        for (int nt = 0; nt < 4; nt++)
            acc[mt][nt] = (f32x4){0.f, 0.f, 0.f, 0.f};

#pragma unroll
    for (int s = 0; s < 6; s++) {
        const int tap = s >> 1, half = s & 1;
#pragma unroll
        for (int nt = 0; nt < 4; nt++) {
            int t = 16 * nt + lo;
            int row = uni ? (t + tap * dil) : (tap * 64 + t);
            int byte = (row * 128 + half * 64 + hi * 16) ^ ((row & 7) << 4);
            s16x8 bx =
                __builtin_bit_cast(s16x8, ((const uint4*)Xs)[byte >> 4]);
            acc[0][nt] = MFMA_BF16(AH[0][s], bx, acc[0][nt], 0, 0, 0);
            acc[1][nt] = MFMA_BF16(AH[1][s], bx, acc[1][nt], 0, 0, 0);
        }
    }

    // ---- gating -> Gs (bf16, swizzled). lane covers c = m0+4hi+r, t=16nt+lo
    const int c0 = m0 + 4 * hi;
#pragma unroll
    for (int nt = 0; nt < 4; nt++) {
        float g[4];
#pragma unroll
        for (int r = 0; r < 4; r++) {
            float hA = acc[0][nt][r] + bA[r];
            float hB = acc[1][nt][r] + bB[r];
            g[r] = fast_tanh(hA) * fast_sigmoid(hB);
        }
        int t = 16 * nt + lo;
        int byte = (t * 128 + c0 * 2) ^ ((t & 7) << 4);
        ((uint2*)Gs)[byte >> 3] =
            make_uint2(pack_bf2(g[0], g[1]), pack_bf2(g[2], g[3]));
    }
    __syncthreads();

    // ---- res GEMM over K=64 ----
    f32x4 acc2[4];
#pragma unroll
    for (int nt = 0; nt < 4; nt++) acc2[nt] = (f32x4){0.f, 0.f, 0.f, 0.f};
#pragma unroll
    for (int s = 0; s < 2; s++) {
#pragma unroll
        for (int nt = 0; nt < 4; nt++) {
            int t = 16 * nt + lo;
            int byte = (t * 128 + s * 64 + hi * 16) ^ ((t & 7) << 4);
            s16x8 bg =
                __builtin_bit_cast(s16x8, ((const uint4*)Gs)[byte >> 4]);
            acc2[nt] = MFMA_BF16(AR[s], bg, acc2[nt], 0, 0, 0);
        }
    }

    // ---- epilogue: actOut = res + rb + actIn (fp32 residual, L2-hot) ----
    float* outB = actOut + (size_t)b * T_LEN * NC;
#pragma unroll
    for (int nt = 0; nt < 4; nt++) {
        int t = 16 * nt + lo;
        size_t base = (size_t)(t0 + t) * 64 + c0;
        float4 inp = *(const float4*)(actB + base);
        float4 o;
        o.x = acc2[nt][0] + rbv[0] + inp.x;
        o.y = acc2[nt][1] + rbv[1] + inp.y;
        o.z = acc2[nt][2] + rbv[2] + inp.z;
        o.w = acc2[nt][3] + rbv[3] + inp.w;
        *(float4*)(outB + base) = o;
    }

    // ---- skip: out[b][t] += sum_c mw[c]*g[t][c]  (wave 0, one lane per t)
    if (tid < 64) {
        int t = tid;
        int swz = (t & 7) << 4;
        float s = 0.f;
#pragma unroll
        for (int j = 0; j < 8; j++) {
            uint4 gv = ((const uint4*)Gs)[((t * 128 + 16 * j) ^ swz) >> 4];
            unsigned uu[4] = {gv.x, gv.y, gv.z, gv.w};
#pragma unroll
            for (int e = 0; e < 4; e++) {
                s += bf2f((unsigned short)(uu[e] & 0xffff)) * mw[j * 8 + 2 * e];
                s += bf2f((unsigned short)(uu[e] >> 16)) * mw[j * 8 + 2 * e + 1];
            }
        }
        skip[(size_t)b * T_LEN + t0 + t] += s;
    }
}

// ------------------------------------------------------------------
extern "C" void kernel_launch(void* const* d_in, const int* in_sizes, int n_in,
                              void* d_out, int out_size, void* d_ws, size_t ws_size,
                              hipStream_t stream) {
    const float* x     = (const float*)d_in[0];
    const float* in_w  = (const float*)d_in[1];
    const float* in_b  = (const float*)d_in[2];
    const float* hid_w = (const float*)d_in[3];
    const float* hid_b = (const float*)d_in[4];
    const float* res_w = (const float*)d_in[5];
    const float* res_b = (const float*)d_in[6];
    const float* mix_w = (const float*)d_in[7];
    const float* mix_b = (const float*)d_in[8];
    float* out = (float*)d_out;

    const size_t actN = (size_t)NB * T_LEN * NC;  // 8388608
    float* A0 = (float*)d_ws;
    float* A1 = A0 + actN;
    unsigned short* Wh = (unsigned short*)(A1 + actN);
    unsigned short* Wr = Wh + (size_t)NL * 128 * 192;

    prep_kernel<<<2048, 256, 0, stream>>>(x, in_w, in_b, hid_w, res_w, mix_b,
                                          A0, Wh, Wr, out);

    static const int dils[NL] = {1, 2, 4, 8, 16, 32, 64, 128, 256,
                                 1, 2, 4, 8, 16, 32, 64, 128, 256};
    const float* src = A0;
    float* dst = A1;
    for (int i = 0; i < NL; i++) {
        layer_kernel<<<dim3(T_LEN / TILE_T, NB), 256, 0, stream>>>(
            src, dst,
            Wh + (size_t)i * 128 * 192,
            hid_b + (size_t)i * 128,
            Wr + (size_t)i * 64 * 64,
            res_b + (size_t)i * 64,
            mix_w + (size_t)i * 64,
            out, dils[i]);
        const float* tmp = src;
        src = dst;
        dst = (float*)tmp;
    }
}

// Round 5
// 497.585 us; speedup vs baseline: 1.3625x; 1.3625x over previous
//
#include <hip/hip_runtime.h>
#include <hip/hip_bf16.h>
#include <math.h>

#define T_LEN 32768
#define NB 4
#define NC 64
#define NL 18
#define TILE_T 64

typedef __attribute__((ext_vector_type(8))) short s16x8;
typedef __attribute__((ext_vector_type(4))) float f32x4;
#define MFMA_BF16 __builtin_amdgcn_mfma_f32_16x16x32_bf16

__device__ inline unsigned short f2bf(float f) {
    unsigned u = __builtin_bit_cast(unsigned, f);
    unsigned r = u + 0x7FFFu + ((u >> 16) & 1u);
    return (unsigned short)(r >> 16);
}
__device__ inline unsigned pack_bf2(float a, float b) {
    return (unsigned)f2bf(a) | ((unsigned)f2bf(b) << 16);
}
__device__ inline float fast_sigmoid(float x) {
    return __builtin_amdgcn_rcpf(1.f + __expf(-x));
}
__device__ inline float fast_tanh(float x) {
    return 1.f - 2.f * __builtin_amdgcn_rcpf(1.f + __expf(2.f * x));
}

// ------------------------------------------------------------------
// prep: A0[b][t][c] fp32 + S0 bf16 shadow; Wh bf16 [L][128co][192K];
//       Wr bf16 [L][64co][64ci]; out init = mix_b; zerobuf = 0
// ------------------------------------------------------------------
__global__ void prep_kernel(const float* __restrict__ x,
                            const float* __restrict__ in_w,
                            const float* __restrict__ in_b,
                            const float* __restrict__ hid_w,
                            const float* __restrict__ res_w,
                            const float* __restrict__ mix_b,
                            float* __restrict__ A0,
                            unsigned short* __restrict__ S0,
                            unsigned short* __restrict__ Wh,
                            unsigned short* __restrict__ Wr,
                            float* __restrict__ out,
                            float* __restrict__ zerobuf) {
    const int nAct = NB * T_LEN * NC;      // 8388608
    const int nW1 = NL * 128 * 192;        // 442368
    const int nW2 = NL * 64 * 64;          // 73728
    const int nOut = NB * T_LEN;           // 131072
    const int total = nAct + nW1 + nW2 + nOut + 32;
    for (int gid = blockIdx.x * blockDim.x + threadIdx.x; gid < total;
         gid += gridDim.x * blockDim.x) {
        if (gid < nAct) {
            int c = gid & 63;
            int t = (gid >> 6) & (T_LEN - 1);
            int b = gid >> 21;
            float v = x[b * T_LEN + t] * in_w[c] + in_b[c];
            A0[gid] = v;
            S0[gid] = f2bf(v);
        } else if (gid < nAct + nW1) {
            int q = gid - nAct;
            int K = q % 192;
            int co = (q / 192) & 127;
            int i = q / (192 * 128);
            int kt = K >> 6, ci = K & 63;
            Wh[q] = f2bf(hid_w[((i * 128 + co) * 64 + ci) * 3 + kt]);
        } else if (gid < nAct + nW1 + nW2) {
            int q = gid - (nAct + nW1);
            int c = q & 63, co = (q >> 6) & 63, i = q >> 12;
            Wr[q] = f2bf(res_w[(i * 64 + co) * 64 + c]);
        } else if (gid < nAct + nW1 + nW2 + nOut) {
            out[gid - (nAct + nW1 + nW2)] = mix_b[0];
        } else {
            zerobuf[gid - (nAct + nW1 + nW2 + nOut)] = 0.f;
        }
    }
}

// ------------------------------------------------------------------
// fused layer. 256 thr = 4 waves; tile = (b, 64 t). Templated on DIL.
// Staging: bf16 shadow -> LDS via global_load_lds (src pre-swizzled).
// Outputs staged in LDS -> full-line coalesced global writes.
// ------------------------------------------------------------------
template <int DIL>
__launch_bounds__(256, 3)
__global__ void layer_kernel(const float* __restrict__ actF,       // fp32 in
                             const unsigned short* __restrict__ actS, // bf16 in
                             float* __restrict__ outF,              // fp32 out
                             unsigned short* __restrict__ outS,     // bf16 out
                             const unsigned short* __restrict__ Wh, // [128][192]
                             const float* __restrict__ hb,          // [128]
                             const unsigned short* __restrict__ Wr, // [64][64]
                             const float* __restrict__ rb,          // [64]
                             const float* __restrict__ mw,          // [64]
                             float* __restrict__ skip,              // [B][T]
                             const float* __restrict__ zerobuf) {
    constexpr bool UNI = (DIL < 64);
    constexpr int R = UNI ? (64 + 2 * DIL) : 192;   // staged rows
    constexpr int SLOTS = R * 8;                     // 16B chunks
    constexpr int JMAX = (SLOTS + 255) / 256;        // lds-load instrs/wave

    __shared__ uint4 Xs[1536];   // staged X rows (swizzled); later out-stage
    __shared__ uint4 Gs[512];    // gated [64t][64c] bf16, swizzled
    __shared__ float Sk[256];    // skip partials [w][t]

    const int tid = threadIdx.x;
    const int w = tid >> 6;
    const int l = tid & 63;
    const int lo = l & 15;
    const int hi = l >> 4;
    const int b = blockIdx.y;
    const int tile = (blockIdx.x & 7) * 64 + (blockIdx.x >> 3);  // XCD swizzle
    const int t0 = tile * TILE_T;
    const int m0 = 16 * w;
    const int c0 = m0 + 4 * hi;

    const float* actB = actF + (size_t)b * T_LEN * NC;
    const unsigned short* shad = actS + (size_t)b * T_LEN * NC;

    // ---- issue async staging: bf16 shadow -> LDS, source pre-swizzled ----
#pragma unroll
    for (int j = 0; j < JMAX; j++) {
        int s = (w * JMAX + j) * 64 + l;
        const void* src;
        if (s >= SLOTS) {
            src = (const void*)(zerobuf + (s & 7) * 4);
        } else {
            int row = s >> 3, ch = s & 7;
            int chunk = ch ^ (row & 7);
            int tg = t0 + (UNI ? (row - 2 * DIL)
                               : (((row >> 6) - 2) * DIL + (row & 63)));
            src = (tg >= 0) ? (const void*)(shad + (size_t)tg * 64 + chunk * 8)
                            : (const void*)(zerobuf + chunk * 4);
        }
        __builtin_amdgcn_global_load_lds(
            (const __attribute__((address_space(1))) unsigned int*)src,
            (__attribute__((address_space(3))) unsigned int*)((char*)Xs +
                                                    (w * JMAX + j) * 1024),
            16, 0, 0);
    }

    // ---- W fragments -> registers ----
    s16x8 AH[2][6];
    s16x8 AR[2];
#pragma unroll
    for (int mt = 0; mt < 2; mt++) {
        const unsigned short* wp = Wh + (size_t)(m0 + 64 * mt + lo) * 192;
#pragma unroll
        for (int s = 0; s < 6; s++)
            AH[mt][s] = *(const s16x8*)(wp + 32 * s + 8 * hi);
    }
#pragma unroll
    for (int s = 0; s < 2; s++)
        AR[s] = *(const s16x8*)(Wr + (size_t)(m0 + lo) * 64 + 32 * s + 8 * hi);

    float bA[4], bB[4], rbv[4];
#pragma unroll
    for (int r = 0; r < 4; r++) {
        bA[r] = hb[c0 + r];
        bB[r] = hb[64 + c0 + r];
        rbv[r] = rb[c0 + r];
    }
    const float4 mw4 = *(const float4*)(mw + c0);

    // ---- residual input (fp32, L2-hot) for epilogue; issue early ----
    float4 inp[4];
#pragma unroll
    for (int nt = 0; nt < 4; nt++)
        inp[nt] = *(const float4*)(actB + (size_t)(t0 + 16 * nt + lo) * 64 + c0);

    __syncthreads();   // staging (+vmcnt drain) complete

    // ---- hid GEMM: acc[mt][nt] over K=192 (3 taps x 64 ci) ----
    f32x4 acc[2][4];
#pragma unroll
    for (int mt = 0; mt < 2; mt++)
#pragma unroll
        for (int nt = 0; nt < 4; nt++)
            acc[mt][nt] = (f32x4){0.f, 0.f, 0.f, 0.f};

#pragma unroll
    for (int s = 0; s < 6; s++) {
        const int tap = s >> 1, half = s & 1;
#pragma unroll
        for (int nt = 0; nt < 4; nt++) {
            int t = 16 * nt + lo;
            int row = UNI ? (t + tap * DIL) : (tap * 64 + t);
            int byte = (row * 128 + half * 64 + hi * 16) ^ ((row & 7) << 4);
            s16x8 bx =
                __builtin_bit_cast(s16x8, ((const uint4*)Xs)[byte >> 4]);
            acc[0][nt] = MFMA_BF16(AH[0][s], bx, acc[0][nt], 0, 0, 0);
            acc[1][nt] = MFMA_BF16(AH[1][s], bx, acc[1][nt], 0, 0, 0);
        }
    }

    // ---- gating -> Gs + skip partials from registers ----
#pragma unroll
    for (int nt = 0; nt < 4; nt++) {
        float g[4];
#pragma unroll
        for (int r = 0; r < 4; r++) {
            float hA = acc[0][nt][r] + bA[r];
            float hB = acc[1][nt][r] + bB[r];
            g[r] = fast_tanh(hA) * fast_sigmoid(hB);
        }
        int t = 16 * nt + lo;
        int byte = (t * 128 + c0 * 2) ^ ((t & 7) << 4);
        ((uint2*)Gs)[byte >> 3] =
            make_uint2(pack_bf2(g[0], g[1]), pack_bf2(g[2], g[3]));
        float sk = g[0] * mw4.x + g[1] * mw4.y + g[2] * mw4.z + g[3] * mw4.w;
        sk += __shfl_xor(sk, 16, 64);
        sk += __shfl_xor(sk, 32, 64);
        if (hi == 0) Sk[w * 64 + nt * 16 + lo] = sk;
    }
    __syncthreads();

    // ---- res GEMM over K=64 ----
    f32x4 acc2[4];
#pragma unroll
    for (int nt = 0; nt < 4; nt++) acc2[nt] = (f32x4){0.f, 0.f, 0.f, 0.f};
#pragma unroll
    for (int s = 0; s < 2; s++) {
#pragma unroll
        for (int nt = 0; nt < 4; nt++) {
            int t = 16 * nt + lo;
            int byte = (t * 128 + s * 64 + hi * 16) ^ ((t & 7) << 4);
            s16x8 bg =
                __builtin_bit_cast(s16x8, ((const uint4*)Gs)[byte >> 4]);
            acc2[nt] = MFMA_BF16(AR[s], bg, acc2[nt], 0, 0, 0);
        }
    }

    // ---- out-stage into LDS (Xs reused): fp32 [64t][64c] + bf16 shadow ----
    char* OutF = (char*)Xs;             // 16 KB
    char* OutB = (char*)Xs + 16384;     // 8 KB
#pragma unroll
    for (int nt = 0; nt < 4; nt++) {
        int t = 16 * nt + lo;
        float4 o;
        o.x = acc2[nt][0] + rbv[0] + inp[nt].x;
        o.y = acc2[nt][1] + rbv[1] + inp[nt].y;
        o.z = acc2[nt][2] + rbv[2] + inp[nt].z;
        o.w = acc2[nt][3] + rbv[3] + inp[nt].w;
        int chunkF = (4 * w + hi) ^ (t & 15);
        *(float4*)(OutF + t * 256 + chunkF * 16) = o;
        int byteB = (t * 128 + c0 * 2) ^ ((t & 7) << 4);
        *(uint2*)(OutB + byteB) =
            make_uint2(pack_bf2(o.x, o.y), pack_bf2(o.z, o.w));
    }

    // ---- skip: out[b][t] += sum_w Sk[w][t] ----
    if (tid < 64) {
        float s2 = Sk[tid] + Sk[64 + tid] + Sk[128 + tid] + Sk[192 + tid];
        skip[(size_t)b * T_LEN + t0 + tid] += s2;
    }
    __syncthreads();

    // ---- coalesced copy-out: full 128B lines ----
    float* gF = outF + (size_t)b * T_LEN * NC + (size_t)t0 * 64;
    unsigned short* gB = outS + (size_t)b * T_LEN * NC + (size_t)t0 * 64;
#pragma unroll
    for (int i = 0; i < 4; i++) {
        int u = i * 256 + tid;          // 1024 uint4 = 16 KB
        int t = u >> 4, ch = u & 15;
        uint4 v = *(const uint4*)(OutF + t * 256 + ((ch ^ (t & 15)) << 4));
        ((uint4*)gF)[u] = v;
    }
#pragma unroll
    for (int i = 0; i < 2; i++) {
        int u = i * 256 + tid;          // 512 uint4 = 8 KB
        int t = u >> 3, ch = u & 7;
        uint4 v = *(const uint4*)(OutB + t * 128 + ((ch ^ (t & 7)) << 4));
        ((uint4*)gB)[u] = v;
    }
}

// ------------------------------------------------------------------
extern "C" void kernel_launch(void* const* d_in, const int* in_sizes, int n_in,
                              void* d_out, int out_size, void* d_ws, size_t ws_size,
                              hipStream_t stream) {
    const float* x     = (const float*)d_in[0];
    const float* in_w  = (const float*)d_in[1];
    const float* in_b  = (const float*)d_in[2];
    const float* hid_w = (const float*)d_in[3];
    const float* hid_b = (const float*)d_in[4];
    const float* res_w = (const float*)d_in[5];
    const float* res_b = (const float*)d_in[6];
    const float* mix_w = (const float*)d_in[7];
    const float* mix_b = (const float*)d_in[8];
    float* out = (float*)d_out;

    const size_t actN = (size_t)NB * T_LEN * NC;  // 8388608
    float* A0 = (float*)d_ws;
    float* A1 = A0 + actN;
    unsigned short* S0 = (unsigned short*)(A1 + actN);
    unsigned short* S1 = S0 + actN;
    unsigned short* Wh = S1 + actN;
    unsigned short* Wr = Wh + (size_t)NL * 128 * 192;
    float* zerobuf = (float*)(Wr + (size_t)NL * 64 * 64);

    prep_kernel<<<2048, 256, 0, stream>>>(x, in_w, in_b, hid_w, res_w, mix_b,
                                          A0, S0, Wh, Wr, out, zerobuf);

    static const int dils[NL] = {1, 2, 4, 8, 16, 32, 64, 128, 256,
                                 1, 2, 4, 8, 16, 32, 64, 128, 256};
    const float* srcF = A0;
    const unsigned short* srcS = S0;
    float* dstF = A1;
    unsigned short* dstS = S1;
    dim3 grid(T_LEN / TILE_T, NB);

#define LAUNCH_LAYER(D)                                                       \
    layer_kernel<D><<<grid, 256, 0, stream>>>(                                \
        srcF, srcS, dstF, dstS, Wh + (size_t)i * 128 * 192,                   \
        hid_b + (size_t)i * 128, Wr + (size_t)i * 64 * 64,                    \
        res_b + (size_t)i * 64, mix_w + (size_t)i * 64, out, zerobuf)

    for (int i = 0; i < NL; i++) {
        switch (dils[i]) {
            case 1:   LAUNCH_LAYER(1);   break;
            case 2:   LAUNCH_LAYER(2);   break;
            case 4:   LAUNCH_LAYER(4);   break;
            case 8:   LAUNCH_LAYER(8);   break;
            case 16:  LAUNCH_LAYER(16);  break;
            case 32:  LAUNCH_LAYER(32);  break;
            case 64:  LAUNCH_LAYER(64);  break;
            case 128: LAUNCH_LAYER(128); break;
            case 256: LAUNCH_LAYER(256); break;
        }
        const float* tF = srcF; srcF = dstF; dstF = (float*)tF;
        const unsigned short* tS = srcS; srcS = dstS; dstS = (unsigned short*)tS;
    }
#undef LAUNCH_LAYER
}